// Round 5
// baseline (170.592 us; speedup 1.0000x reference)
//
#include <hip/hip_runtime.h>

#define NH   8
#define NS   256
#define NT   1024
#define ND   64

typedef __attribute__((ext_vector_type(4))) float f32x4;
typedef __attribute__((ext_vector_type(8))) short short8;

__device__ __forceinline__ short f2bf(float f) {
    union { float f; unsigned u; } v; v.f = f;
    unsigned r = v.u + 0x7FFFu + ((v.u >> 16) & 1u);   // RNE
    return (short)(r >> 16);
}

// Raw barrier: LDS-ordering only. Avoids the compiler's s_waitcnt vmcnt(0)
// drain before s_barrier (__syncthreads), which was parking the whole block
// until all outstanding HBM stores completed (phase-aligned across blocks ->
// store pipe idles in bursts -> ~40% of achievable BW).
#define RAW_BARRIER() do { \
    asm volatile("s_waitcnt lgkmcnt(0)" ::: "memory"); \
    __builtin_amdgcn_s_barrier(); \
} while (0)

// out[b,t,s] = q[b,t,:] . ( s <= t/4 ? e1[h, 255-(t/4-s), :] : e2[h, s-t/4, :] ), h=b%8
// Block per (h, a=t/4): 64 q-rows x 256 s-cols GEMM, K=64, bf16 MFMA.
// B operand global->reg (e tables 4 MB, L2/L3-resident). A staged in lA with
// XOR-swizzled chunks (verified). Epilogue bounces acc through a SEPARATE
// 16-row fbuf (no lA aliasing -> no false deps) in 4 chunks, with raw
// barriers only -> stores stay in flight across chunks and blocks.
// LDS: 8192 (lA) + 16640 (fbuf) = 24832 B.
__global__ __launch_bounds__(256, 4) void srel_kernel(
    const float* __restrict__ q, const float* __restrict__ e1,
    const float* __restrict__ e2, float* __restrict__ out)
{
    const int h   = blockIdx.x >> 8;
    const int a   = blockIdx.x & 255;
    const int tid = threadIdx.x;
    const int wave = tid >> 6;
    const int lane = tid & 63;

    __shared__ __align__(16) char smem[64*64*2 + 16*260*4];   // 24832 B
    unsigned short* lA = (unsigned short*)smem;                // 64 rows x 64 shorts
    float* fbuf = (float*)(smem + 64*64*2);                    // 16 rows x 260 f32

    // ---- stage A: q tile (f32 -> bf16 in VALU), swizzled chunks (verified) ----
    {
        const int m    = tid >> 2;
        const int part = tid & 3;
        const int b    = (m >> 2) * NH + h;
        const int t    = a * 4 + (m & 3);
        const f32x4* src = (const f32x4*)(q + ((size_t)b * NT + t) * ND + part * 16);
        f32x4 v0 = src[0], v1 = src[1], v2 = src[2], v3 = src[3];
        short8 p0, p1;
        p0[0]=f2bf(v0[0]); p0[1]=f2bf(v0[1]); p0[2]=f2bf(v0[2]); p0[3]=f2bf(v0[3]);
        p0[4]=f2bf(v1[0]); p0[5]=f2bf(v1[1]); p0[6]=f2bf(v1[2]); p0[7]=f2bf(v1[3]);
        p1[0]=f2bf(v2[0]); p1[1]=f2bf(v2[1]); p1[2]=f2bf(v2[2]); p1[3]=f2bf(v2[3]);
        p1[4]=f2bf(v3[0]); p1[5]=f2bf(v3[1]); p1[6]=f2bf(v3[2]); p1[7]=f2bf(v3[3]);
        const int sw = m & 7;
        *(short8*)(lA + m * 64 + (((2*part)   ^ sw) * 8)) = p0;
        *(short8*)(lA + m * 64 + (((2*part+1) ^ sw) * 8)) = p1;
    }

    // ---- B-frag row pointers: s-col of this lane per tn ----
    const int lrow = lane & 15;
    const int quad = lane >> 4;
    const float* rp[4];
    #pragma unroll
    for (int tn = 0; tn < 4; ++tn) {
        const int s = wave * 64 + tn * 16 + lrow;
        rp[tn] = (s <= a)
            ? (e1 + ((size_t)(h * NS + 255 - a + s)) * ND)
            : (e2 + ((size_t)(h * NS + s - a)) * ND);
    }

    RAW_BARRIER();   // lA writes visible to all waves (LDS-only ordering)

    // ---- MFMA: wave w -> cols [w*64, w*64+64), 16 tiles of 16x16, K=64 ----
    f32x4 acc[4][4] = {};
    #pragma unroll
    for (int kk2 = 0; kk2 < 2; ++kk2) {
        const int lc  = 4 * kk2 + quad;            // logical K-chunk 0..7
        const int swz = (lc ^ (lrow & 7)) * 8;     // lA phys chunk (XOR swizzle)
        short8 afr[4], bfr[4];
        #pragma unroll
        for (int tn = 0; tn < 4; ++tn) {
            const f32x4* bp = (const f32x4*)(rp[tn] + lc * 8);
            f32x4 v0 = bp[0], v1 = bp[1];
            short8 pk;
            pk[0]=f2bf(v0[0]); pk[1]=f2bf(v0[1]); pk[2]=f2bf(v0[2]); pk[3]=f2bf(v0[3]);
            pk[4]=f2bf(v1[0]); pk[5]=f2bf(v1[1]); pk[6]=f2bf(v1[2]); pk[7]=f2bf(v1[3]);
            bfr[tn] = pk;
        }
        #pragma unroll
        for (int tm = 0; tm < 4; ++tm)
            afr[tm] = *(const short8*)(lA + (tm * 16 + lrow) * 64 + swz);
        #pragma unroll
        for (int tm = 0; tm < 4; ++tm)
            #pragma unroll
            for (int tn = 0; tn < 4; ++tn)
                acc[tm][tn] = __builtin_amdgcn_mfma_f32_16x16x32_bf16(
                    afr[tm], bfr[tn], acc[tm][tn], 0, 0, 0);
    }

    // ---- epilogue: 4 chunks of 16 rows through fbuf, raw barriers only ----
    // C/D layout: col = lane&15, row-in-tile = quad*4 + reg. (verified)
    // fbuf is disjoint from lA -> chunk 0 needs no leading barrier.
    #pragma unroll
    for (int c = 0; c < 4; ++c) {
        if (c) RAW_BARRIER();    // all waves' chunk c-1 fbuf reads complete
        #pragma unroll
        for (int r = 0; r < 4; ++r) {
            const int rl = quad * 4 + r;          // 0..15
            #pragma unroll
            for (int tn = 0; tn < 4; ++tn)
                fbuf[rl * 260 + wave * 64 + tn * 16 + lrow] = acc[c][tn][r];
        }
        RAW_BARRIER();           // all waves' fbuf writes visible
        #pragma unroll
        for (int i = 0; i < 4; ++i) {
            const int rl = i * 4 + wave;          // 0..15
            const int m  = c * 16 + rl;
            const int b  = (m >> 2) * NH + h;
            const int t  = a * 4 + (m & 3);
            f32x4 v = *(const f32x4*)(fbuf + rl * 260 + lane * 4);
            *(f32x4*)(out + ((size_t)b * NT + t) * NS + lane * 4) = v;
        }
    }
}

extern "C" void kernel_launch(void* const* d_in, const int* in_sizes, int n_in,
                              void* d_out, int out_size, void* d_ws, size_t ws_size,
                              hipStream_t stream) {
    (void)in_sizes; (void)n_in; (void)ws_size; (void)out_size; (void)d_ws;
    const float* q  = (const float*)d_in[0];
    const float* e1 = (const float*)d_in[1];
    const float* e2 = (const float*)d_in[2];
    float* out = (float*)d_out;

    srel_kernel<<<dim3(NH * NS), dim3(256), 0, stream>>>(q, e1, e2, out);
}

// Round 6
// 167.825 us; speedup vs baseline: 1.0165x; 1.0165x over previous
//
#include <hip/hip_runtime.h>

#define NH   8
#define NS   256
#define NT   1024
#define ND   64

typedef __attribute__((ext_vector_type(4))) float f32x4;
typedef __attribute__((ext_vector_type(8))) short short8;

__device__ __forceinline__ short f2bf(float f) {
    union { float f; unsigned u; } v; v.f = f;
    unsigned r = v.u + 0x7FFFu + ((v.u >> 16) & 1u);   // RNE
    return (short)(r >> 16);
}

// Raw barrier: LDS-ordering only (no vmcnt(0) drain -> stores stay in flight).
#define RAW_BARRIER() do { \
    asm volatile("s_waitcnt lgkmcnt(0)" ::: "memory"); \
    __builtin_amdgcn_s_barrier(); \
} while (0)

// out[b,t,s] = q[b,t,:] . ( s <= t/4 ? e1[h, 255-(t/4-s), :] : e2[h, s-t/4, :] ), h=b%8
// Block per (h, p): TWO adjacent a-tiles (a = 2p, 2p+1), each 64 q-rows x 256
// s-cols, K=64, bf16 MFMA. Grid = 1024 = exactly 4 blocks/CU (one full wave,
// no tail). Both q tiles staged behind ONE barrier; then MFMA0 -> epi0 ->
// MFMA1 -> epi1 with raw barriers only, so stores stream across the tile
// boundary and stage/launch overhead is amortized 2x. Adjacent tiles' e-row
// windows overlap by 254 rows -> L2-warm B loads for tile 1.
// LDS: lA0 8K + lA1 8K + fbuf 16.6K = 33024 B -> 4 blocks/CU.
__global__ __launch_bounds__(256, 4) void srel_kernel(
    const float* __restrict__ q, const float* __restrict__ e1,
    const float* __restrict__ e2, float* __restrict__ out)
{
    const int h   = blockIdx.x >> 7;
    const int p   = blockIdx.x & 127;
    const int tid = threadIdx.x;
    const int wave = tid >> 6;
    const int lane = tid & 63;

    __shared__ __align__(16) char smem[2 * 64*64*2 + 16*260*4];   // 33024 B
    unsigned short* lA0 = (unsigned short*)smem;                   // tile 0: 64x64 shorts
    unsigned short* lA1 = (unsigned short*)(smem + 64*64*2);       // tile 1
    float* fbuf = (float*)(smem + 2 * 64*64*2);                    // 16 rows x 260 f32

    // ---- stage A: BOTH q tiles (f32 -> bf16), swizzled chunks (verified) ----
    {
        const int m    = tid >> 2;
        const int part = tid & 3;
        const int b    = (m >> 2) * NH + h;
        const int t0   = (2 * p) * 4 + (m & 3);
        const f32x4* s0 = (const f32x4*)(q + ((size_t)b * NT + t0) * ND + part * 16);
        const f32x4* s1 = (const f32x4*)(q + ((size_t)b * NT + t0 + 4) * ND + part * 16);
        f32x4 v0 = s0[0], v1 = s0[1], v2 = s0[2], v3 = s0[3];
        f32x4 w0 = s1[0], w1 = s1[1], w2 = s1[2], w3 = s1[3];
        short8 p0, p1, q0, q1;
        p0[0]=f2bf(v0[0]); p0[1]=f2bf(v0[1]); p0[2]=f2bf(v0[2]); p0[3]=f2bf(v0[3]);
        p0[4]=f2bf(v1[0]); p0[5]=f2bf(v1[1]); p0[6]=f2bf(v1[2]); p0[7]=f2bf(v1[3]);
        p1[0]=f2bf(v2[0]); p1[1]=f2bf(v2[1]); p1[2]=f2bf(v2[2]); p1[3]=f2bf(v2[3]);
        p1[4]=f2bf(v3[0]); p1[5]=f2bf(v3[1]); p1[6]=f2bf(v3[2]); p1[7]=f2bf(v3[3]);
        q0[0]=f2bf(w0[0]); q0[1]=f2bf(w0[1]); q0[2]=f2bf(w0[2]); q0[3]=f2bf(w0[3]);
        q0[4]=f2bf(w1[0]); q0[5]=f2bf(w1[1]); q0[6]=f2bf(w1[2]); q0[7]=f2bf(w1[3]);
        q1[0]=f2bf(w2[0]); q1[1]=f2bf(w2[1]); q1[2]=f2bf(w2[2]); q1[3]=f2bf(w2[3]);
        q1[4]=f2bf(w3[0]); q1[5]=f2bf(w3[1]); q1[6]=f2bf(w3[2]); q1[7]=f2bf(w3[3]);
        const int sw = m & 7;
        *(short8*)(lA0 + m * 64 + (((2*part)   ^ sw) * 8)) = p0;
        *(short8*)(lA0 + m * 64 + (((2*part+1) ^ sw) * 8)) = p1;
        *(short8*)(lA1 + m * 64 + (((2*part)   ^ sw) * 8)) = q0;
        *(short8*)(lA1 + m * 64 + (((2*part+1) ^ sw) * 8)) = q1;
    }

    RAW_BARRIER();   // both lA tiles visible (LDS-only ordering)

    const int lrow = lane & 15;
    const int quad = lane >> 4;

    #pragma unroll
    for (int j = 0; j < 2; ++j) {
        const int a = 2 * p + j;
        const unsigned short* lA = j ? lA1 : lA0;

        // ---- B-frag row pointers for this tile ----
        const float* rp[4];
        #pragma unroll
        for (int tn = 0; tn < 4; ++tn) {
            const int s = wave * 64 + tn * 16 + lrow;
            rp[tn] = (s <= a)
                ? (e1 + ((size_t)(h * NS + 255 - a + s)) * ND)
                : (e2 + ((size_t)(h * NS + s - a)) * ND);
        }

        // ---- MFMA: wave w -> cols [w*64, w*64+64), 16 tiles 16x16, K=64 ----
        f32x4 acc[4][4] = {};
        #pragma unroll
        for (int kk2 = 0; kk2 < 2; ++kk2) {
            const int lc  = 4 * kk2 + quad;            // logical K-chunk 0..7
            const int swz = (lc ^ (lrow & 7)) * 8;     // lA phys chunk (XOR swizzle)
            short8 afr[4], bfr[4];
            #pragma unroll
            for (int tn = 0; tn < 4; ++tn) {
                const f32x4* bp = (const f32x4*)(rp[tn] + lc * 8);
                f32x4 b0 = bp[0], b1 = bp[1];
                short8 pk;
                pk[0]=f2bf(b0[0]); pk[1]=f2bf(b0[1]); pk[2]=f2bf(b0[2]); pk[3]=f2bf(b0[3]);
                pk[4]=f2bf(b1[0]); pk[5]=f2bf(b1[1]); pk[6]=f2bf(b1[2]); pk[7]=f2bf(b1[3]);
                bfr[tn] = pk;
            }
            #pragma unroll
            for (int tm = 0; tm < 4; ++tm)
                afr[tm] = *(const short8*)(lA + (tm * 16 + lrow) * 64 + swz);
            #pragma unroll
            for (int tm = 0; tm < 4; ++tm)
                #pragma unroll
                for (int tn = 0; tn < 4; ++tn)
                    acc[tm][tn] = __builtin_amdgcn_mfma_f32_16x16x32_bf16(
                        afr[tm], bfr[tn], acc[tm][tn], 0, 0, 0);
        }

        // ---- epilogue: 4 chunks of 16 rows through fbuf, raw barriers only ----
        // C/D layout: col = lane&15, row-in-tile = quad*4 + reg. (verified)
        #pragma unroll
        for (int c = 0; c < 4; ++c) {
            if (j || c) RAW_BARRIER();   // prior chunk's fbuf reads complete
            #pragma unroll
            for (int r = 0; r < 4; ++r) {
                const int rl = quad * 4 + r;          // 0..15
                #pragma unroll
                for (int tn = 0; tn < 4; ++tn)
                    fbuf[rl * 260 + wave * 64 + tn * 16 + lrow] = acc[c][tn][r];
            }
            RAW_BARRIER();               // fbuf writes visible
            #pragma unroll
            for (int i = 0; i < 4; ++i) {
                const int rl = i * 4 + wave;          // 0..15
                const int m  = c * 16 + rl;
                const int b  = (m >> 2) * NH + h;
                const int t  = a * 4 + (m & 3);
                f32x4 v = *(const f32x4*)(fbuf + rl * 260 + lane * 4);
                *(f32x4*)(out + ((size_t)b * NT + t) * NS + lane * 4) = v;
            }
        }
    }
}

extern "C" void kernel_launch(void* const* d_in, const int* in_sizes, int n_in,
                              void* d_out, int out_size, void* d_ws, size_t ws_size,
                              hipStream_t stream) {
    (void)in_sizes; (void)n_in; (void)ws_size; (void)out_size; (void)d_ws;
    const float* q  = (const float*)d_in[0];
    const float* e1 = (const float*)d_in[1];
    const float* e2 = (const float*)d_in[2];
    float* out = (float*)d_out;

    srel_kernel<<<dim3(NH * 128), dim3(256), 0, stream>>>(q, e1, e2, out);
}

// Round 7
// 163.380 us; speedup vs baseline: 1.0441x; 1.0272x over previous
//
#include <hip/hip_runtime.h>
#include <hip/hip_bf16.h>

#define NH   8
#define NS   256
#define NT   1024
#define ND   64

typedef __attribute__((ext_vector_type(4))) float f32x4;
typedef __attribute__((ext_vector_type(8))) short short8;

// Pack 8 f32 -> 8 bf16 (RNE). Scalar/paired header casts: compiler lowers
// these to v_cvt_pk_bf16_f32 on gfx950 (2 elems/inst) — ~8x fewer VALU ops
// than manual bit-math RNE, bit-identical results (both RNE) on non-NaN.
__device__ __forceinline__ short8 pack8(f32x4 a, f32x4 b) {
    union { __hip_bfloat162 h; unsigned u; } c0, c1, c2, c3;
    c0.h = __float22bfloat162_rn(make_float2(a[0], a[1]));
    c1.h = __float22bfloat162_rn(make_float2(a[2], a[3]));
    c2.h = __float22bfloat162_rn(make_float2(b[0], b[1]));
    c3.h = __float22bfloat162_rn(make_float2(b[2], b[3]));
    union { unsigned u[4]; short8 s; } r;
    r.u[0] = c0.u; r.u[1] = c1.u; r.u[2] = c2.u; r.u[3] = c3.u;
    return r.s;
}

// Raw barrier: LDS-ordering only (no vmcnt(0) drain -> stores stay in flight).
#define RAW_BARRIER() do { \
    asm volatile("s_waitcnt lgkmcnt(0)" ::: "memory"); \
    __builtin_amdgcn_s_barrier(); \
} while (0)

// out[b,t,s] = q[b,t,:] . ( s <= t/4 ? e1[h, 255-(t/4-s), :] : e2[h, s-t/4, :] ), h=b%8
// Block per (h, p): TWO adjacent a-tiles (a = 2p, 2p+1), each 64 q-rows x 256
// s-cols, K=64, bf16 MFMA. Grid = 1024 = exactly 4 blocks/CU, all co-resident.
// Both q tiles staged behind ONE barrier; MFMA0 -> epi0 -> MFMA1 -> epi1 with
// raw barriers only. B operand global->reg (e tables 4 MB, L2/L3-resident).
// LDS: lA0 8K + lA1 8K + fbuf 16.6K = 33024 B -> 4 blocks/CU.
__global__ __launch_bounds__(256, 4) void srel_kernel(
    const float* __restrict__ q, const float* __restrict__ e1,
    const float* __restrict__ e2, float* __restrict__ out)
{
    const int h   = blockIdx.x >> 7;
    const int p   = blockIdx.x & 127;
    const int tid = threadIdx.x;
    const int wave = tid >> 6;
    const int lane = tid & 63;

    __shared__ __align__(16) char smem[2 * 64*64*2 + 16*260*4];   // 33024 B
    unsigned short* lA0 = (unsigned short*)smem;                   // tile 0: 64x64 shorts
    unsigned short* lA1 = (unsigned short*)(smem + 64*64*2);       // tile 1
    float* fbuf = (float*)(smem + 2 * 64*64*2);                    // 16 rows x 260 f32

    // ---- stage A: BOTH q tiles (f32 -> bf16 via cvt_pk), swizzled chunks ----
    {
        const int m    = tid >> 2;
        const int part = tid & 3;
        const int b    = (m >> 2) * NH + h;
        const int t0   = (2 * p) * 4 + (m & 3);
        const f32x4* s0 = (const f32x4*)(q + ((size_t)b * NT + t0) * ND + part * 16);
        const f32x4* s1 = (const f32x4*)(q + ((size_t)b * NT + t0 + 4) * ND + part * 16);
        f32x4 v0 = s0[0], v1 = s0[1], v2 = s0[2], v3 = s0[3];
        f32x4 w0 = s1[0], w1 = s1[1], w2 = s1[2], w3 = s1[3];
        short8 p0 = pack8(v0, v1), p1 = pack8(v2, v3);
        short8 q0 = pack8(w0, w1), q1 = pack8(w2, w3);
        const int sw = m & 7;
        *(short8*)(lA0 + m * 64 + (((2*part)   ^ sw) * 8)) = p0;
        *(short8*)(lA0 + m * 64 + (((2*part+1) ^ sw) * 8)) = p1;
        *(short8*)(lA1 + m * 64 + (((2*part)   ^ sw) * 8)) = q0;
        *(short8*)(lA1 + m * 64 + (((2*part+1) ^ sw) * 8)) = q1;
    }

    RAW_BARRIER();   // both lA tiles visible (LDS-only ordering)

    const int lrow = lane & 15;
    const int quad = lane >> 4;

    #pragma unroll
    for (int j = 0; j < 2; ++j) {
        const int a = 2 * p + j;
        const unsigned short* lA = j ? lA1 : lA0;

        // ---- B-frag row pointers for this tile ----
        const float* rp[4];
        #pragma unroll
        for (int tn = 0; tn < 4; ++tn) {
            const int s = wave * 64 + tn * 16 + lrow;
            rp[tn] = (s <= a)
                ? (e1 + ((size_t)(h * NS + 255 - a + s)) * ND)
                : (e2 + ((size_t)(h * NS + s - a)) * ND);
        }

        // ---- MFMA: wave w -> cols [w*64, w*64+64), 16 tiles 16x16, K=64 ----
        f32x4 acc[4][4] = {};
        #pragma unroll
        for (int kk2 = 0; kk2 < 2; ++kk2) {
            const int lc  = 4 * kk2 + quad;            // logical K-chunk 0..7
            const int swz = (lc ^ (lrow & 7)) * 8;     // lA phys chunk (XOR swizzle)
            short8 afr[4], bfr[4];
            #pragma unroll
            for (int tn = 0; tn < 4; ++tn) {
                const f32x4* bp = (const f32x4*)(rp[tn] + lc * 8);
                f32x4 b0 = bp[0], b1 = bp[1];
                bfr[tn] = pack8(b0, b1);
            }
            #pragma unroll
            for (int tm = 0; tm < 4; ++tm)
                afr[tm] = *(const short8*)(lA + (tm * 16 + lrow) * 64 + swz);
            #pragma unroll
            for (int tm = 0; tm < 4; ++tm)
                #pragma unroll
                for (int tn = 0; tn < 4; ++tn)
                    acc[tm][tn] = __builtin_amdgcn_mfma_f32_16x16x32_bf16(
                        afr[tm], bfr[tn], acc[tm][tn], 0, 0, 0);
        }

        // ---- epilogue: 4 chunks of 16 rows through fbuf, raw barriers only ----
        // C/D layout: col = lane&15, row-in-tile = quad*4 + reg. (verified)
        #pragma unroll
        for (int c = 0; c < 4; ++c) {
            if (j || c) RAW_BARRIER();   // prior chunk's fbuf reads complete
            #pragma unroll
            for (int r = 0; r < 4; ++r) {
                const int rl = quad * 4 + r;          // 0..15
                #pragma unroll
                for (int tn = 0; tn < 4; ++tn)
                    fbuf[rl * 260 + wave * 64 + tn * 16 + lrow] = acc[c][tn][r];
            }
            RAW_BARRIER();               // fbuf writes visible
            #pragma unroll
            for (int i = 0; i < 4; ++i) {
                const int rl = i * 4 + wave;          // 0..15
                const int m  = c * 16 + rl;
                const int b  = (m >> 2) * NH + h;
                const int t  = a * 4 + (m & 3);
                f32x4 v = *(const f32x4*)(fbuf + rl * 260 + lane * 4);
                *(f32x4*)(out + ((size_t)b * NT + t) * NS + lane * 4) = v;
            }
        }
    }
}

extern "C" void kernel_launch(void* const* d_in, const int* in_sizes, int n_in,
                              void* d_out, int out_size, void* d_ws, size_t ws_size,
                              hipStream_t stream) {
    (void)in_sizes; (void)n_in; (void)ws_size; (void)out_size; (void)d_ws;
    const float* q  = (const float*)d_in[0];
    const float* e1 = (const float*)d_in[1];
    const float* e2 = (const float*)d_in[2];
    float* out = (float*)d_out;

    srel_kernel<<<dim3(NH * 128), dim3(256), 0, stream>>>(q, e1, e2, out);
}

// Round 9
// 162.082 us; speedup vs baseline: 1.0525x; 1.0080x over previous
//
#include <hip/hip_runtime.h>
#include <hip/hip_bf16.h>

#define NH   8
#define NS   256
#define NT   1024
#define ND   64
#define ESZ  (NH * NS * ND)   // 131072 elements per e-table

typedef __attribute__((ext_vector_type(4))) float f32x4;
typedef __attribute__((ext_vector_type(8))) short short8;

// Pack 8 f32 -> 8 bf16 (RNE) via v_cvt_pk_bf16_f32 (compiler-lowered).
__device__ __forceinline__ short8 pack8(f32x4 a, f32x4 b) {
    union { __hip_bfloat162 h; unsigned u; } c0, c1, c2, c3;
    c0.h = __float22bfloat162_rn(make_float2(a[0], a[1]));
    c1.h = __float22bfloat162_rn(make_float2(a[2], a[3]));
    c2.h = __float22bfloat162_rn(make_float2(b[0], b[1]));
    c3.h = __float22bfloat162_rn(make_float2(b[2], b[3]));
    union { unsigned u[4]; short8 s; } r;
    r.u[0] = c0.u; r.u[1] = c1.u; r.u[2] = c2.u; r.u[3] = c3.u;
    return r.s;
}

// Raw barrier: LDS-ordering only (no vmcnt(0) drain -> stores stay in flight).
#define RAW_BARRIER() do { \
    asm volatile("s_waitcnt lgkmcnt(0)" ::: "memory"); \
    __builtin_amdgcn_s_barrier(); \
} while (0)

// One-shot: e1,e2 (f32) -> bf16 table in ws. eb[0:ESZ)=e1, [ESZ:2*ESZ)=e2.
// The harness fills the 512 MiB ws EVERY iteration unconditionally (profiled
// rounds 2-7, ws untouched) — so using ws costs nothing extra.
__global__ __launch_bounds__(256) void cvt_e_kernel(
    const float* __restrict__ e1, const float* __restrict__ e2,
    unsigned short* __restrict__ eb)
{
    const int i = (blockIdx.x * 256 + threadIdx.x) * 8;   // 8 elems/thread
    const float* src = (i < ESZ) ? (e1 + i) : (e2 + (i - ESZ));
    f32x4 v0 = ((const f32x4*)src)[0];
    f32x4 v1 = ((const f32x4*)src)[1];
    *(short8*)(eb + i) = pack8(v0, v1);
}

// out[b,t,s] = q[b,t,:] . ( s <= t/4 ? e1[h, 255-(t/4-s), :] : e2[h, s-t/4, :] ), h=b%8
// Block per (h, p): TWO adjacent a-tiles (a = 2p, 2p+1), each 64 q-rows x 256
// s-cols, K=64, bf16 MFMA. Grid = 1024 = exactly 4 blocks/CU, co-resident.
// Both q tiles staged behind ONE barrier; MFMA0 -> epi0 -> MFMA1 -> epi1 with
// raw barriers only. B operand: direct global->reg short8 loads from the bf16
// e-table (L2-resident, no conversion in the hot loop).
// LDS: lA0 8K + lA1 8K + fbuf 16.6K = 33024 B -> 4 blocks/CU.
__global__ __launch_bounds__(256, 4) void srel_kernel(
    const float* __restrict__ q, const unsigned short* __restrict__ eb,
    float* __restrict__ out)
{
    const int h   = blockIdx.x >> 7;
    const int p   = blockIdx.x & 127;
    const int tid = threadIdx.x;
    const int wave = tid >> 6;
    const int lane = tid & 63;

    __shared__ __align__(16) char smem[2 * 64*64*2 + 16*260*4];   // 33024 B
    unsigned short* lA0 = (unsigned short*)smem;                   // tile 0: 64x64 shorts
    unsigned short* lA1 = (unsigned short*)(smem + 64*64*2);       // tile 1
    float* fbuf = (float*)(smem + 2 * 64*64*2);                    // 16 rows x 260 f32

    // ---- stage A: BOTH q tiles (f32 -> bf16 via cvt_pk), swizzled chunks ----
    {
        const int m    = tid >> 2;
        const int part = tid & 3;
        const int b    = (m >> 2) * NH + h;
        const int t0   = (2 * p) * 4 + (m & 3);
        const f32x4* s0 = (const f32x4*)(q + ((size_t)b * NT + t0) * ND + part * 16);
        const f32x4* s1 = (const f32x4*)(q + ((size_t)b * NT + t0 + 4) * ND + part * 16);
        f32x4 v0 = s0[0], v1 = s0[1], v2 = s0[2], v3 = s0[3];
        f32x4 w0 = s1[0], w1 = s1[1], w2 = s1[2], w3 = s1[3];
        short8 p0 = pack8(v0, v1), p1 = pack8(v2, v3);
        short8 q0 = pack8(w0, w1), q1 = pack8(w2, w3);
        const int sw = m & 7;
        *(short8*)(lA0 + m * 64 + (((2*part)   ^ sw) * 8)) = p0;
        *(short8*)(lA0 + m * 64 + (((2*part+1) ^ sw) * 8)) = p1;
        *(short8*)(lA1 + m * 64 + (((2*part)   ^ sw) * 8)) = q0;
        *(short8*)(lA1 + m * 64 + (((2*part+1) ^ sw) * 8)) = q1;
    }

    RAW_BARRIER();   // both lA tiles visible (LDS-only ordering)

    const int lrow = lane & 15;
    const int quad = lane >> 4;

    #pragma unroll
    for (int j = 0; j < 2; ++j) {
        const int a = 2 * p + j;
        const unsigned short* lA = j ? lA1 : lA0;

        // ---- B-frag row pointers for this tile (bf16 table) ----
        const unsigned short* rp[4];
        #pragma unroll
        for (int tn = 0; tn < 4; ++tn) {
            const int s = wave * 64 + tn * 16 + lrow;
            rp[tn] = (s <= a)
                ? (eb + ((size_t)(h * NS + 255 - a + s)) * ND)
                : (eb + (size_t)ESZ + ((size_t)(h * NS + s - a)) * ND);
        }

        // ---- MFMA: wave w -> cols [w*64, w*64+64), 16 tiles 16x16, K=64 ----
        f32x4 acc[4][4] = {};
        #pragma unroll
        for (int kk2 = 0; kk2 < 2; ++kk2) {
            const int lc  = 4 * kk2 + quad;            // logical K-chunk 0..7
            const int swz = (lc ^ (lrow & 7)) * 8;     // lA phys chunk (XOR swizzle)
            short8 afr[4], bfr[4];
            #pragma unroll
            for (int tn = 0; tn < 4; ++tn)
                bfr[tn] = *(const short8*)(rp[tn] + lc * 8);
            #pragma unroll
            for (int tm = 0; tm < 4; ++tm)
                afr[tm] = *(const short8*)(lA + (tm * 16 + lrow) * 64 + swz);
            #pragma unroll
            for (int tm = 0; tm < 4; ++tm)
                #pragma unroll
                for (int tn = 0; tn < 4; ++tn)
                    acc[tm][tn] = __builtin_amdgcn_mfma_f32_16x16x32_bf16(
                        afr[tm], bfr[tn], acc[tm][tn], 0, 0, 0);
        }

        // ---- epilogue: 4 chunks of 16 rows through fbuf, raw barriers only ----
        // C/D layout: col = lane&15, row-in-tile = quad*4 + reg. (verified)
        #pragma unroll
        for (int c = 0; c < 4; ++c) {
            if (j || c) RAW_BARRIER();   // prior chunk's fbuf reads complete
            #pragma unroll
            for (int r = 0; r < 4; ++r) {
                const int rl = quad * 4 + r;          // 0..15
                #pragma unroll
                for (int tn = 0; tn < 4; ++tn)
                    fbuf[rl * 260 + wave * 64 + tn * 16 + lrow] = acc[c][tn][r];
            }
            RAW_BARRIER();               // fbuf writes visible
            #pragma unroll
            for (int i = 0; i < 4; ++i) {
                const int rl = i * 4 + wave;          // 0..15
                const int m  = c * 16 + rl;
                const int b  = (m >> 2) * NH + h;
                const int t  = a * 4 + (m & 3);
                f32x4 v = *(const f32x4*)(fbuf + rl * 260 + lane * 4);
                *(f32x4*)(out + ((size_t)b * NT + t) * NS + lane * 4) = v;
            }
        }
    }
}

extern "C" void kernel_launch(void* const* d_in, const int* in_sizes, int n_in,
                              void* d_out, int out_size, void* d_ws, size_t ws_size,
                              hipStream_t stream) {
    (void)in_sizes; (void)n_in; (void)ws_size; (void)out_size;
    const float* q  = (const float*)d_in[0];
    const float* e1 = (const float*)d_in[1];
    const float* e2 = (const float*)d_in[2];
    float* out = (float*)d_out;
    unsigned short* eb = (unsigned short*)d_ws;

    cvt_e_kernel<<<dim3(2 * ESZ / (256 * 8)), dim3(256), 0, stream>>>(e1, e2, eb);
    srel_kernel<<<dim3(NH * 128), dim3(256), 0, stream>>>(q, eb, out);
}